// Round 1
// baseline (352.307 us; speedup 1.0000x reference)
//
#include <hip/hip_runtime.h>

#define CONF_TH 0.9f
#define NMS_TH  0.5f
#define KDET    512
#define CAP     2048   // candidate capacity, power of two for bitonic sort
#define NCLS    80
#define CH      85
#define NBATCH  32

__global__ __launch_bounds__(1024) void yolo_predict_kernel(
    const float* __restrict__ pred, int A,
    float* __restrict__ out_dets,   // [B][KDET][7]
    float* __restrict__ out_keep)   // [B][KDET]
{
    const int b   = blockIdx.x;
    const int tid = threadIdx.x;
    const float* __restrict__ p = pred + (size_t)b * A * CH;

    __shared__ unsigned long long keys[CAP];
    __shared__ int s_count;
    __shared__ float bx1[KDET], by1[KDET], bx2[KDET], by2[KDET];
    __shared__ float s_obj[KDET], s_conf[KDET];
    __shared__ int   s_cls[KDET];
    __shared__ int   s_keep[KDET];

    if (tid == 0) s_count = 0;
    __syncthreads();

    // ---- Phase A: scan obj channel, collect candidates ----
    for (int a = tid; a < A; a += blockDim.x) {
        float logit = p[(size_t)a * CH + 4];
        float obj = 1.0f / (1.0f + expf(-logit));
        if (obj >= CONF_TH) {
            int pos = atomicAdd(&s_count, 1);
            if (pos < CAP) {
                unsigned ob = __float_as_uint(obj);  // obj in (0,1): positive, monotonic as uint
                keys[pos] = ((unsigned long long)ob << 32)
                          | (unsigned long long)(~(unsigned)a); // tie: smaller idx => larger key
            }
        }
    }
    __syncthreads();
    const int count = min(s_count, CAP);

    // pad rest with 0 (sorts to the end under descending order)
    for (int i = tid; i < CAP; i += blockDim.x)
        if (i >= count) keys[i] = 0ull;
    __syncthreads();

    // ---- Phase B: bitonic sort, descending ----
    for (int k = 2; k <= CAP; k <<= 1) {
        for (int j = k >> 1; j > 0; j >>= 1) {
            for (int i = tid; i < CAP; i += blockDim.x) {
                int ixj = i ^ j;
                if (ixj > i) {
                    unsigned long long a0 = keys[i], a1 = keys[ixj];
                    bool desc = ((i & k) == 0);
                    bool sw = desc ? (a0 < a1) : (a0 > a1);
                    if (sw) { keys[i] = a1; keys[ixj] = a0; }
                }
            }
            __syncthreads();
        }
    }

    const int nval = min(count, KDET);

    // ---- Phase C: gather rows for top-K, compute box/cls ----
    if (tid < KDET) {
        const int k = tid;
        if (k < nval) {
            unsigned long long key = keys[k];
            int a = (int)(~(unsigned)(key & 0xFFFFFFFFull));
            float obj = __uint_as_float((unsigned)(key >> 32));
            const float* __restrict__ row = p + (size_t)a * CH;
            float cx = row[0], cy = row[1], w = row[2], h = row[3];
            bx1[k] = cx - w * 0.5f;
            by1[k] = cy - h * 0.5f;
            bx2[k] = cx + w * 0.5f;
            by2[k] = cy + h * 0.5f;
            float best = row[5];
            int bid = 0;
            #pragma unroll 4
            for (int c = 1; c < NCLS; ++c) {
                float v = row[5 + c];
                if (v > best) { best = v; bid = c; }  // strict > keeps first max (JAX argmax)
            }
            s_conf[k] = 1.0f / (1.0f + expf(-best));
            s_cls[k]  = bid;
            s_obj[k]  = obj;
            s_keep[k] = 1;
        } else {
            bx1[k] = 0.f; by1[k] = 0.f; bx2[k] = 0.f; by2[k] = 0.f;
            s_obj[k] = 0.f; s_conf[k] = 0.f; s_cls[k] = 0; s_keep[k] = 0;
        }
    }
    __syncthreads();

    // ---- Phase D: sequential greedy NMS, single wave (no barriers needed) ----
    if (tid < 64) {
        volatile int* vk = s_keep;
        for (int i = 0; i < nval; ++i) {
            if (vk[i] == 0) { __builtin_amdgcn_wave_barrier(); continue; }
            float x1 = bx1[i], y1 = by1[i], x2 = bx2[i], y2 = by2[i];
            int   ci = s_cls[i];
            float ai = fmaxf(x2 - x1, 0.f) * fmaxf(y2 - y1, 0.f);
            #pragma unroll
            for (int s = 0; s < KDET / 64; ++s) {
                int j = s * 64 + tid;
                if (j > i && vk[j] && s_cls[j] == ci) {
                    float jx1 = bx1[j], jy1 = by1[j], jx2 = bx2[j], jy2 = by2[j];
                    float aj = fmaxf(jx2 - jx1, 0.f) * fmaxf(jy2 - jy1, 0.f);
                    float xx1 = fmaxf(x1, jx1), yy1 = fmaxf(y1, jy1);
                    float xx2 = fminf(x2, jx2), yy2 = fminf(y2, jy2);
                    float ww = fmaxf(xx2 - xx1, 0.f), hh = fmaxf(yy2 - yy1, 0.f);
                    float inter = ww * hh;
                    float uni = ai + aj - inter;
                    float iou = inter / fmaxf(uni, 1e-9f);
                    if (iou > NMS_TH) vk[j] = 0;
                }
            }
            __builtin_amdgcn_wave_barrier();
        }
    }
    __syncthreads();

    // ---- Phase E: write outputs (every element, every launch) ----
    if (tid < KDET) {
        const int k = tid;
        float kp = s_keep[k] ? 1.0f : 0.0f;
        float* d = out_dets + ((size_t)b * KDET + k) * 7;
        d[0] = bx1[k] * kp;
        d[1] = by1[k] * kp;
        d[2] = bx2[k] * kp;
        d[3] = by2[k] * kp;
        d[4] = s_obj[k]  * kp;
        d[5] = s_conf[k] * kp;
        d[6] = (float)s_cls[k] * kp;
        out_keep[(size_t)b * KDET + k] = kp;
    }
}

extern "C" void kernel_launch(void* const* d_in, const int* in_sizes, int n_in,
                              void* d_out, int out_size, void* d_ws, size_t ws_size,
                              hipStream_t stream) {
    const float* pred = (const float*)d_in[0];
    const int A = in_sizes[0] / (NBATCH * CH);   // 22743
    float* dets = (float*)d_out;                  // [32][512][7]
    float* keep = dets + (size_t)NBATCH * KDET * 7;
    yolo_predict_kernel<<<NBATCH, 1024, 0, stream>>>(pred, A, dets, keep);
}

// Round 2
// 175.162 us; speedup vs baseline: 2.0113x; 2.0113x over previous
//
#include <hip/hip_runtime.h>

#define CONF_TH 0.9f
#define NMS_TH  0.5f
#define KDET    512
#define CAP     1024   // candidate capacity per batch (expected ~320)
#define NCLS    80
#define CH      85
#define NBATCH  32

typedef unsigned long long ull;

// ---------------- Kernel 1: full-GPU candidate scan ----------------
__global__ void yolo_scan(const float* __restrict__ pred, int A, int cap,
                          ull* __restrict__ cand, int* __restrict__ cnt)
{
    const int b = blockIdx.y;
    const int a = blockIdx.x * blockDim.x + threadIdx.x;
    if (a >= A) return;
    float logit = pred[((size_t)b * A + a) * CH + 4];
    float obj = 1.0f / (1.0f + expf(-logit));
    if (obj >= CONF_TH) {
        int pos = atomicAdd(&cnt[b], 1);
        if (pos < cap) {
            // key: obj (positive float, monotonic as uint) desc, then index asc
            cand[(size_t)b * CAP + pos] =
                ((ull)__float_as_uint(obj) << 32) | (ull)(~(unsigned)a);
        }
    }
}

// ---------------- Kernel 2: per-batch select + NMS + write ----------------
__global__ __launch_bounds__(1024) void yolo_finalize(
    const float* __restrict__ pred, int A, int cap,
    const ull* __restrict__ cand, const int* __restrict__ cnt_g,
    float* __restrict__ out_dets,   // [B][KDET][7]
    float* __restrict__ out_keep)   // [B][KDET]
{
    const int b = blockIdx.x;
    const int tid = threadIdx.x;
    const float* __restrict__ p = pred + (size_t)b * A * CH;

    __shared__ ull keys[CAP];
    __shared__ ull skeys[KDET];
    __shared__ float bx1[KDET], by1[KDET], bx2[KDET], by2[KDET];
    __shared__ float s_obj[KDET], s_conf[KDET];
    __shared__ int   s_cls[KDET];
    __shared__ unsigned sup[KDET][16];   // suppression bitmask rows (32 KB)
    __shared__ unsigned keepw[KDET / 32];

    int cnt = cnt_g[b];
    if (cnt > cap) cnt = cap;
    const int nval = cnt < KDET ? cnt : KDET;

    if (tid < cnt) keys[tid] = cand[(size_t)b * CAP + tid];
    __syncthreads();

    // ---- rank selection (O(n) per thread, broadcast LDS reads) ----
    if (tid < cnt) {
        ull key = keys[tid];
        int rank = 0;
        for (int j = 0; j < cnt; ++j) rank += (keys[j] > key) ? 1 : 0;
        if (rank < KDET) skeys[rank] = key;   // keys distinct (idx embedded)
    }
    // zero suppression matrix: 512*16 words / 1024 threads = 8 each
    #pragma unroll
    for (int i = 0; i < (KDET * 16) / 1024; ++i)
        ((unsigned*)sup)[tid + i * 1024] = 0u;
    __syncthreads();

    // ---- gather top-K rows, compute boxes + class ----
    if (tid < KDET) {
        const int k = tid;
        if (k < nval) {
            ull key = skeys[k];
            int a = (int)(~(unsigned)(key & 0xFFFFFFFFull));
            const float* __restrict__ row = p + (size_t)a * CH;
            float cx = row[0], cy = row[1], w = row[2], h = row[3];
            bx1[k] = cx - w * 0.5f;
            by1[k] = cy - h * 0.5f;
            bx2[k] = cx + w * 0.5f;
            by2[k] = cy + h * 0.5f;
            float best = row[5];
            int bid = 0;
            #pragma unroll 4
            for (int c = 1; c < NCLS; ++c) {
                float v = row[5 + c];
                if (v > best) { best = v; bid = c; }  // first-max (JAX argmax)
            }
            s_conf[k] = 1.0f / (1.0f + expf(-best));
            s_cls[k]  = bid;
            s_obj[k]  = __uint_as_float((unsigned)(key >> 32));
        } else {
            bx1[k] = 0.f; by1[k] = 0.f; bx2[k] = 0.f; by2[k] = 0.f;
            s_obj[k] = 0.f; s_conf[k] = 0.f; s_cls[k] = 0;
        }
    }
    __syncthreads();

    // ---- build suppression bitmask: thread i owns row i ----
    if (tid < nval) {
        const int i = tid;
        float x1 = bx1[i], y1 = by1[i], x2 = bx2[i], y2 = by2[i];
        int   ci = s_cls[i];
        float ai = fmaxf(x2 - x1, 0.f) * fmaxf(y2 - y1, 0.f);
        for (int j = i + 1; j < nval; ++j) {
            if (s_cls[j] != ci) continue;
            float jx1 = bx1[j], jy1 = by1[j], jx2 = bx2[j], jy2 = by2[j];
            float aj = fmaxf(jx2 - jx1, 0.f) * fmaxf(jy2 - jy1, 0.f);
            float xx1 = fmaxf(x1, jx1), yy1 = fmaxf(y1, jy1);
            float xx2 = fminf(x2, jx2), yy2 = fminf(y2, jy2);
            float ww = fmaxf(xx2 - xx1, 0.f), hh = fmaxf(yy2 - yy1, 0.f);
            float inter = ww * hh;
            float uni = ai + aj - inter;
            float iou = inter / fmaxf(uni, 1e-9f);
            if (iou > NMS_TH) sup[i][j >> 5] |= (1u << (j & 31));  // exclusive row owner
        }
    }
    __syncthreads();

    // ---- sequential greedy pass: one wave, register bitmask sweep ----
    if (tid < 64) {
        const int l = tid;
        unsigned keep_w;
        if ((l + 1) * 32 <= nval)      keep_w = 0xFFFFFFFFu;
        else if (l * 32 >= nval)       keep_w = 0u;
        else                           keep_w = (1u << (nval - l * 32)) - 1u;
        for (int i = 0; i < nval; ++i) {
            int w = i >> 5;
            unsigned kb = (unsigned)__shfl((int)keep_w, w);     // broadcast word holding bit i
            unsigned sw = (l < 16) ? sup[i][l] : 0u;            // prefetchable, indep of keep
            unsigned mask = ((kb >> (i & 31)) & 1u) ? ~sw : 0xFFFFFFFFu;
            keep_w &= mask;
        }
        if (l < KDET / 32) keepw[l] = keep_w;
    }
    __syncthreads();

    // ---- write outputs (every element, every launch) ----
    if (tid < KDET) {
        const int k = tid;
        float kp = ((keepw[k >> 5] >> (k & 31)) & 1u) ? 1.0f : 0.0f;
        float* d = out_dets + ((size_t)b * KDET + k) * 7;
        d[0] = bx1[k] * kp;
        d[1] = by1[k] * kp;
        d[2] = bx2[k] * kp;
        d[3] = by2[k] * kp;
        d[4] = s_obj[k]  * kp;
        d[5] = s_conf[k] * kp;
        d[6] = (float)s_cls[k] * kp;
        out_keep[(size_t)b * KDET + k] = kp;
    }
}

extern "C" void kernel_launch(void* const* d_in, const int* in_sizes, int n_in,
                              void* d_out, int out_size, void* d_ws, size_t ws_size,
                              hipStream_t stream) {
    const float* pred = (const float*)d_in[0];
    const int A = in_sizes[0] / (NBATCH * CH);   // 22743

    int* cnt  = (int*)d_ws;                       // 32 counters
    ull* cand = (ull*)((char*)d_ws + 256);        // 32 x CAP keys
    // safety clamp if workspace is unexpectedly small
    size_t need = 256 + (size_t)NBATCH * CAP * sizeof(ull);
    int cap = CAP;
    if (ws_size < need) {
        size_t per = (ws_size > 256 ? ws_size - 256 : 0) / (NBATCH * sizeof(ull));
        cap = per < (size_t)CAP ? (int)per : CAP;
    }

    hipMemsetAsync(d_ws, 0, 256, stream);         // zero counters every launch

    dim3 sg((A + 255) / 256, NBATCH);
    yolo_scan<<<sg, 256, 0, stream>>>(pred, A, cap, cand, cnt);

    float* dets = (float*)d_out;                  // [32][512][7]
    float* keep = dets + (size_t)NBATCH * KDET * 7;
    yolo_finalize<<<NBATCH, 1024, 0, stream>>>(pred, A, cap, cand, cnt, dets, keep);
}

// Round 3
// 174.778 us; speedup vs baseline: 2.0157x; 1.0022x over previous
//
#include <hip/hip_runtime.h>

#define CONF_TH 0.9f
#define NMS_TH  0.5f
#define KDET    512
#define CAP     1024   // candidate capacity per batch (expected ~320)
#define NCLS    80
#define CH      85
#define NBATCH  32

typedef unsigned long long ull;

// ---------------- Kernel 0: zero the per-batch counters (replaces memset) ----
__global__ void yolo_zero(int* __restrict__ cnt) {
    if (threadIdx.x < NBATCH) cnt[threadIdx.x] = 0;
}

// ---------------- Kernel 1: full-GPU candidate scan ----------------
__global__ void yolo_scan(const float* __restrict__ pred, int A, int cap,
                          ull* __restrict__ cand, int* __restrict__ cnt)
{
    const int b = blockIdx.y;
    const int a = blockIdx.x * blockDim.x + threadIdx.x;
    if (a >= A) return;
    float logit = pred[((size_t)b * A + a) * CH + 4];
    float obj = 1.0f / (1.0f + expf(-logit));
    if (obj >= CONF_TH) {
        int pos = atomicAdd(&cnt[b], 1);
        if (pos < cap) {
            // key: obj (positive float, monotonic as uint) desc, then index asc
            cand[(size_t)b * CAP + pos] =
                ((ull)__float_as_uint(obj) << 32) | (ull)(~(unsigned)a);
        }
    }
}

// ---------------- Kernel 2: per-batch select + NMS + write ----------------
__global__ __launch_bounds__(1024) void yolo_finalize(
    const float* __restrict__ pred, int A, int cap,
    const ull* __restrict__ cand, const int* __restrict__ cnt_g,
    float* __restrict__ out_dets,   // [B][KDET][7]
    float* __restrict__ out_keep)   // [B][KDET]
{
    const int b = blockIdx.x;
    const int tid = threadIdx.x;
    const float* __restrict__ p = pred + (size_t)b * A * CH;

    __shared__ ull keys[CAP];
    __shared__ ull skeys[KDET];
    __shared__ float bx1[KDET], by1[KDET], bx2[KDET], by2[KDET];
    __shared__ float s_obj[KDET], s_conf[KDET];
    __shared__ int   s_cls[KDET];
    __shared__ unsigned sup[KDET][16];   // suppression bitmask rows (32 KB)
    __shared__ unsigned keepw[KDET / 32];

    int cnt = cnt_g[b];
    if (cnt > cap) cnt = cap;
    const int nval = cnt < KDET ? cnt : KDET;

    if (tid < cnt) keys[tid] = cand[(size_t)b * CAP + tid];
    __syncthreads();

    // ---- rank selection (O(n) per thread, broadcast LDS reads) ----
    if (tid < cnt) {
        ull key = keys[tid];
        int rank = 0;
        for (int j = 0; j < cnt; ++j) rank += (keys[j] > key) ? 1 : 0;
        if (rank < KDET) skeys[rank] = key;   // keys distinct (idx embedded)
    }
    // zero suppression matrix: 512*16 words / 1024 threads = 8 each
    #pragma unroll
    for (int i = 0; i < (KDET * 16) / 1024; ++i)
        ((unsigned*)sup)[tid + i * 1024] = 0u;
    __syncthreads();

    // ---- gather top-K rows, compute boxes + class ----
    if (tid < KDET) {
        const int k = tid;
        if (k < nval) {
            ull key = skeys[k];
            int a = (int)(~(unsigned)(key & 0xFFFFFFFFull));
            const float* __restrict__ row = p + (size_t)a * CH;
            float cx = row[0], cy = row[1], w = row[2], h = row[3];
            bx1[k] = cx - w * 0.5f;
            by1[k] = cy - h * 0.5f;
            bx2[k] = cx + w * 0.5f;
            by2[k] = cy + h * 0.5f;
            float best = row[5];
            int bid = 0;
            #pragma unroll 4
            for (int c = 1; c < NCLS; ++c) {
                float v = row[5 + c];
                if (v > best) { best = v; bid = c; }  // first-max (JAX argmax)
            }
            s_conf[k] = 1.0f / (1.0f + expf(-best));
            s_cls[k]  = bid;
            s_obj[k]  = __uint_as_float((unsigned)(key >> 32));
        } else {
            bx1[k] = 0.f; by1[k] = 0.f; bx2[k] = 0.f; by2[k] = 0.f;
            s_obj[k] = 0.f; s_conf[k] = 0.f; s_cls[k] = 0;
        }
    }
    __syncthreads();

    // ---- build suppression bitmask: thread i owns row i ----
    if (tid < nval) {
        const int i = tid;
        float x1 = bx1[i], y1 = by1[i], x2 = bx2[i], y2 = by2[i];
        int   ci = s_cls[i];
        float ai = fmaxf(x2 - x1, 0.f) * fmaxf(y2 - y1, 0.f);
        for (int j = i + 1; j < nval; ++j) {
            if (s_cls[j] != ci) continue;
            float jx1 = bx1[j], jy1 = by1[j], jx2 = bx2[j], jy2 = by2[j];
            float aj = fmaxf(jx2 - jx1, 0.f) * fmaxf(jy2 - jy1, 0.f);
            float xx1 = fmaxf(x1, jx1), yy1 = fmaxf(y1, jy1);
            float xx2 = fminf(x2, jx2), yy2 = fminf(y2, jy2);
            float ww = fmaxf(xx2 - xx1, 0.f), hh = fmaxf(yy2 - yy1, 0.f);
            float inter = ww * hh;
            float uni = ai + aj - inter;
            float iou = inter / fmaxf(uni, 1e-9f);
            if (iou > NMS_TH) sup[i][j >> 5] |= (1u << (j & 31));  // exclusive row owner
        }
    }
    __syncthreads();

    // ---- sequential greedy pass: one wave, register bitmask sweep ----
    if (tid < 64) {
        const int l = tid;
        unsigned keep_w;
        if ((l + 1) * 32 <= nval)      keep_w = 0xFFFFFFFFu;
        else if (l * 32 >= nval)       keep_w = 0u;
        else                           keep_w = (1u << (nval - l * 32)) - 1u;
        for (int i = 0; i < nval; ++i) {
            int w = i >> 5;
            unsigned kb = (unsigned)__shfl((int)keep_w, w);     // broadcast word holding bit i
            unsigned sw = (l < 16) ? sup[i][l] : 0u;            // prefetchable, indep of keep
            unsigned mask = ((kb >> (i & 31)) & 1u) ? ~sw : 0xFFFFFFFFu;
            keep_w &= mask;
        }
        if (l < KDET / 32) keepw[l] = keep_w;
    }
    __syncthreads();

    // ---- write outputs (every element, every launch) ----
    if (tid < KDET) {
        const int k = tid;
        float kp = ((keepw[k >> 5] >> (k & 31)) & 1u) ? 1.0f : 0.0f;
        float* d = out_dets + ((size_t)b * KDET + k) * 7;
        d[0] = bx1[k] * kp;
        d[1] = by1[k] * kp;
        d[2] = bx2[k] * kp;
        d[3] = by2[k] * kp;
        d[4] = s_obj[k]  * kp;
        d[5] = s_conf[k] * kp;
        d[6] = (float)s_cls[k] * kp;
        out_keep[(size_t)b * KDET + k] = kp;
    }
}

extern "C" void kernel_launch(void* const* d_in, const int* in_sizes, int n_in,
                              void* d_out, int out_size, void* d_ws, size_t ws_size,
                              hipStream_t stream) {
    const float* pred = (const float*)d_in[0];
    const int A = in_sizes[0] / (NBATCH * CH);   // 22743

    int* cnt  = (int*)d_ws;                       // 32 counters
    ull* cand = (ull*)((char*)d_ws + 256);        // 32 x CAP keys
    // safety clamp if workspace is unexpectedly small
    size_t need = 256 + (size_t)NBATCH * CAP * sizeof(ull);
    int cap = CAP;
    if (ws_size < need) {
        size_t per = (ws_size > 256 ? ws_size - 256 : 0) / (NBATCH * sizeof(ull));
        cap = per < (size_t)CAP ? (int)per : CAP;
    }

    yolo_zero<<<1, 64, 0, stream>>>(cnt);         // zero counters (no memset node)

    dim3 sg((A + 255) / 256, NBATCH);
    yolo_scan<<<sg, 256, 0, stream>>>(pred, A, cap, cand, cnt);

    float* dets = (float*)d_out;                  // [32][512][7]
    float* keep = dets + (size_t)NBATCH * KDET * 7;
    yolo_finalize<<<NBATCH, 1024, 0, stream>>>(pred, A, cap, cand, cnt, dets, keep);
}

// Round 4
// 152.168 us; speedup vs baseline: 2.3152x; 1.1486x over previous
//
#include <hip/hip_runtime.h>

#define CONF_TH 0.9f
#define NMS_TH  0.5f
#define KDET    512
#define CAP     1024   // candidate capacity per batch (expected ~320)
#define NCLS    80
#define CH      85
#define NBATCH  32

typedef unsigned long long ull;

// ---------------- Kernel 0: zero the per-batch counters ----------------
__global__ void yolo_zero(int* __restrict__ cnt) {
    if (threadIdx.x < NBATCH) cnt[threadIdx.x] = 0;
}

// ---------------- Kernel 1: full-GPU candidate scan (4 anchors/thread) ----
__global__ __launch_bounds__(256) void yolo_scan(
    const float* __restrict__ pred, int A, int cap,
    ull* __restrict__ cand, int* __restrict__ cnt)
{
    const int b = blockIdx.y;
    const int a0 = blockIdx.x * 1024 + threadIdx.x;
    const float* __restrict__ pb = pred + (size_t)b * A * CH + 4;

    float lg[4];
    #pragma unroll
    for (int u = 0; u < 4; ++u) {
        int a = a0 + u * 256;
        lg[u] = (a < A) ? pb[(size_t)a * CH] : -100.0f;  // sigmoid(-100)≈0 < th
    }
    #pragma unroll
    for (int u = 0; u < 4; ++u) {
        float obj = 1.0f / (1.0f + expf(-lg[u]));
        if (obj >= CONF_TH) {
            int a = a0 + u * 256;
            int pos = atomicAdd(&cnt[b], 1);
            if (pos < cap) {
                // key: obj (positive float, monotonic as uint) desc, then index asc
                cand[(size_t)b * CAP + pos] =
                    ((ull)__float_as_uint(obj) << 32) | (ull)(~(unsigned)a);
            }
        }
    }
}

// ---------------- Kernel 2: per-candidate decode (full coalesced parallel) --
__global__ __launch_bounds__(1024) void yolo_decode(
    const float* __restrict__ pred, int A, int cap,
    const ull* __restrict__ cand, const int* __restrict__ cnt_g,
    float* __restrict__ rec)   // [B][CAP][8]: x1 y1 x2 y2 obj conf cls pad
{
    const int b = blockIdx.x;
    const int t = threadIdx.x;
    int cnt = cnt_g[b];
    if (cnt > cap) cnt = cap;
    if (t >= cnt) return;

    ull key = cand[(size_t)b * CAP + t];
    int a = (int)(~(unsigned)(key & 0xFFFFFFFFull));
    const float* __restrict__ row = pred + ((size_t)b * A + a) * CH;

    float cx = row[0], cy = row[1], w = row[2], h = row[3];
    float best = row[5];
    int bid = 0;
    #pragma unroll 4
    for (int c = 1; c < NCLS; ++c) {
        float v = row[5 + c];
        if (v > best) { best = v; bid = c; }   // first-max (JAX argmax)
    }
    float4 r0, r1;
    r0.x = cx - w * 0.5f;
    r0.y = cy - h * 0.5f;
    r0.z = cx + w * 0.5f;
    r0.w = cy + h * 0.5f;
    r1.x = __uint_as_float((unsigned)(key >> 32));   // obj
    r1.y = 1.0f / (1.0f + expf(-best));              // cls_conf
    r1.z = (float)bid;
    r1.w = 0.0f;
    float4* out = (float4*)(rec + ((size_t)b * CAP + t) * 8);
    out[0] = r0;
    out[1] = r1;
}

// ---------------- Kernel 3: per-batch select + NMS + write ----------------
__global__ __launch_bounds__(1024) void yolo_finalize(
    int cap,
    const ull* __restrict__ cand, const int* __restrict__ cnt_g,
    const float* __restrict__ rec,
    float* __restrict__ out_dets,   // [B][KDET][7]
    float* __restrict__ out_keep)   // [B][KDET]
{
    const int b = blockIdx.x;
    const int tid = threadIdx.x;

    __shared__ ull keys[CAP];
    __shared__ float bx1[KDET], by1[KDET], bx2[KDET], by2[KDET];
    __shared__ float s_obj[KDET], s_conf[KDET];
    __shared__ int   s_cls[KDET];
    __shared__ unsigned sup[KDET][16];   // suppression bitmask rows (32 KB)
    __shared__ unsigned keepw[KDET / 32];

    int cnt = cnt_g[b];
    if (cnt > cap) cnt = cap;
    const int nval = cnt < KDET ? cnt : KDET;

    if (tid < cnt) keys[tid] = cand[(size_t)b * CAP + tid];
    // zero LDS det arrays for ranks >= nval (and all, harmlessly)
    if (tid < KDET) {
        bx1[tid] = 0.f; by1[tid] = 0.f; bx2[tid] = 0.f; by2[tid] = 0.f;
        s_obj[tid] = 0.f; s_conf[tid] = 0.f; s_cls[tid] = 0;
    }
    #pragma unroll
    for (int i = 0; i < (KDET * 16) / 1024; ++i)
        ((unsigned*)sup)[tid + i * 1024] = 0u;
    __syncthreads();

    // ---- rank selection; winners pull their decoded record ----
    if (tid < cnt) {
        ull key = keys[tid];
        int rank = 0;
        for (int j = 0; j < cnt; ++j) rank += (keys[j] > key) ? 1 : 0;
        if (rank < KDET) {   // keys distinct (idx embedded) -> ranks unique
            const float4* r = (const float4*)(rec + ((size_t)b * CAP + tid) * 8);
            float4 r0 = r[0], r1 = r[1];
            bx1[rank] = r0.x; by1[rank] = r0.y;
            bx2[rank] = r0.z; by2[rank] = r0.w;
            s_obj[rank] = r1.x; s_conf[rank] = r1.y;
            s_cls[rank] = (int)r1.z;
        }
    }
    __syncthreads();

    // ---- build suppression bitmask: thread i owns row i ----
    if (tid < nval) {
        const int i = tid;
        float x1 = bx1[i], y1 = by1[i], x2 = bx2[i], y2 = by2[i];
        int   ci = s_cls[i];
        float ai = fmaxf(x2 - x1, 0.f) * fmaxf(y2 - y1, 0.f);
        for (int j = i + 1; j < nval; ++j) {
            if (s_cls[j] != ci) continue;
            float jx1 = bx1[j], jy1 = by1[j], jx2 = bx2[j], jy2 = by2[j];
            float aj = fmaxf(jx2 - jx1, 0.f) * fmaxf(jy2 - jy1, 0.f);
            float xx1 = fmaxf(x1, jx1), yy1 = fmaxf(y1, jy1);
            float xx2 = fminf(x2, jx2), yy2 = fminf(y2, jy2);
            float ww = fmaxf(xx2 - xx1, 0.f), hh = fmaxf(yy2 - yy1, 0.f);
            float inter = ww * hh;
            float uni = ai + aj - inter;
            float iou = inter / fmaxf(uni, 1e-9f);
            if (iou > NMS_TH) sup[i][j >> 5] |= (1u << (j & 31));
        }
    }
    __syncthreads();

    // ---- sequential greedy pass: one wave, register bitmask sweep ----
    if (tid < 64) {
        const int l = tid;
        unsigned keep_w;
        if ((l + 1) * 32 <= nval)      keep_w = 0xFFFFFFFFu;
        else if (l * 32 >= nval)       keep_w = 0u;
        else                           keep_w = (1u << (nval - l * 32)) - 1u;
        for (int i = 0; i < nval; ++i) {
            int w = i >> 5;
            unsigned kb = (unsigned)__shfl((int)keep_w, w);   // word holding bit i
            unsigned sw = (l < 16) ? sup[i][l] : 0u;
            unsigned mask = ((kb >> (i & 31)) & 1u) ? ~sw : 0xFFFFFFFFu;
            keep_w &= mask;
        }
        if (l < KDET / 32) keepw[l] = keep_w;
    }
    __syncthreads();

    // ---- write outputs (every element, every launch) ----
    if (tid < KDET) {
        const int k = tid;
        float kp = ((keepw[k >> 5] >> (k & 31)) & 1u) ? 1.0f : 0.0f;
        float* d = out_dets + ((size_t)b * KDET + k) * 7;
        d[0] = bx1[k] * kp;
        d[1] = by1[k] * kp;
        d[2] = bx2[k] * kp;
        d[3] = by2[k] * kp;
        d[4] = s_obj[k]  * kp;
        d[5] = s_conf[k] * kp;
        d[6] = (float)s_cls[k] * kp;
        out_keep[(size_t)b * KDET + k] = kp;
    }
}

extern "C" void kernel_launch(void* const* d_in, const int* in_sizes, int n_in,
                              void* d_out, int out_size, void* d_ws, size_t ws_size,
                              hipStream_t stream) {
    const float* pred = (const float*)d_in[0];
    const int A = in_sizes[0] / (NBATCH * CH);   // 22743

    int*   cnt  = (int*)d_ws;                          // 32 counters
    ull*   cand = (ull*)((char*)d_ws + 256);           // 32 x CAP keys (256 KB)
    float* rec  = (float*)((char*)d_ws + 256 + (size_t)NBATCH * CAP * sizeof(ull));
    int cap = CAP;                                     // ws is ~1 GB; need ~1.3 MB

    yolo_zero<<<1, 64, 0, stream>>>(cnt);

    dim3 sg((A + 1023) / 1024, NBATCH);
    yolo_scan<<<sg, 256, 0, stream>>>(pred, A, cap, cand, cnt);

    yolo_decode<<<NBATCH, 1024, 0, stream>>>(pred, A, cap, cand, cnt, rec);

    float* dets = (float*)d_out;                  // [32][512][7]
    float* keep = dets + (size_t)NBATCH * KDET * 7;
    yolo_finalize<<<NBATCH, 1024, 0, stream>>>(cap, cand, cnt, rec, dets, keep);
}

// Round 5
// 150.215 us; speedup vs baseline: 2.3454x; 1.0130x over previous
//
#include <hip/hip_runtime.h>

#define CONF_TH 0.9f
#define NMS_TH  0.5f
#define KDET    512
#define CAP     1024   // candidate capacity per batch (expected ~320)
#define NCLS    80
#define CH      85
#define NBATCH  32

typedef unsigned long long ull;

// ---------------- Kernel 0: zero the per-batch counters ----------------
__global__ void yolo_zero(int* __restrict__ cnt) {
    if (threadIdx.x < NBATCH) cnt[threadIdx.x] = 0;
}

// ------- Kernel 1: full-GPU scan + inline per-candidate decode -------
__global__ __launch_bounds__(256) void yolo_scan_decode(
    const float* __restrict__ pred, int A, int cap,
    ull* __restrict__ cand, int* __restrict__ cnt,
    float* __restrict__ rec)   // [B][CAP][8]: x1 y1 x2 y2 obj conf cls pad
{
    const int b = blockIdx.y;
    const int a0 = blockIdx.x * 1024 + threadIdx.x;
    const float* __restrict__ pbase = pred + (size_t)b * A * CH;

    float lg[4];
    #pragma unroll
    for (int u = 0; u < 4; ++u) {
        int a = a0 + u * 256;
        lg[u] = (a < A) ? pbase[(size_t)a * CH + 4] : -100.0f;  // sigmoid(-100)≈0
    }
    #pragma unroll
    for (int u = 0; u < 4; ++u) {
        float obj = 1.0f / (1.0f + expf(-lg[u]));
        if (obj >= CONF_TH) {
            int a = a0 + u * 256;
            int pos = atomicAdd(&cnt[b], 1);
            if (pos < cap) {
                // key: obj (positive f32, monotonic as uint) desc, then index asc
                cand[(size_t)b * CAP + pos] =
                    ((ull)__float_as_uint(obj) << 32) | (ull)(~(unsigned)a);

                // inline decode of this row
                const float* __restrict__ row = pbase + (size_t)a * CH;
                float cx = row[0], cy = row[1], w = row[2], h = row[3];
                float best = row[5];
                int bid = 0;
                #pragma unroll 4
                for (int c = 1; c < NCLS; ++c) {
                    float v = row[5 + c];
                    if (v > best) { best = v; bid = c; }   // first-max (JAX argmax)
                }
                float4 r0, r1;
                r0.x = cx - w * 0.5f;
                r0.y = cy - h * 0.5f;
                r0.z = cx + w * 0.5f;
                r0.w = cy + h * 0.5f;
                r1.x = obj;
                r1.y = 1.0f / (1.0f + expf(-best));        // cls_conf
                r1.z = (float)bid;
                r1.w = 0.0f;
                float4* out = (float4*)(rec + ((size_t)b * CAP + pos) * 8);
                out[0] = r0;
                out[1] = r1;
            }
        }
    }
}

// ---------------- Kernel 2: per-batch select + NMS + write ----------------
__global__ __launch_bounds__(1024) void yolo_finalize(
    int cap,
    const ull* __restrict__ cand, const int* __restrict__ cnt_g,
    const float* __restrict__ rec,
    float* __restrict__ out_dets,   // [B][KDET][7]
    float* __restrict__ out_keep)   // [B][KDET]
{
    const int b = blockIdx.x;
    const int tid = threadIdx.x;

    __shared__ ull keys[CAP];
    __shared__ float bx1[KDET], by1[KDET], bx2[KDET], by2[KDET];
    __shared__ float s_obj[KDET], s_conf[KDET];
    __shared__ int   s_cls[KDET];
    __shared__ unsigned sup[KDET][16];   // suppression bitmask rows (32 KB)
    __shared__ unsigned keepw[KDET / 32];

    int cnt = cnt_g[b];
    if (cnt > cap) cnt = cap;
    const int nval = cnt < KDET ? cnt : KDET;

    if (tid < cnt) keys[tid] = cand[(size_t)b * CAP + tid];
    if (tid < KDET) {
        bx1[tid] = 0.f; by1[tid] = 0.f; bx2[tid] = 0.f; by2[tid] = 0.f;
        s_obj[tid] = 0.f; s_conf[tid] = 0.f; s_cls[tid] = 0;
    }
    #pragma unroll
    for (int i = 0; i < (KDET * 16) / 1024; ++i)
        ((unsigned*)sup)[tid + i * 1024] = 0u;
    __syncthreads();

    // ---- rank selection; winners pull their decoded record ----
    if (tid < cnt) {
        ull key = keys[tid];
        int rank = 0;
        for (int j = 0; j < cnt; ++j) rank += (keys[j] > key) ? 1 : 0;
        if (rank < KDET) {   // keys distinct (idx embedded) -> ranks unique
            const float4* r = (const float4*)(rec + ((size_t)b * CAP + tid) * 8);
            float4 r0 = r[0], r1 = r[1];
            bx1[rank] = r0.x; by1[rank] = r0.y;
            bx2[rank] = r0.z; by2[rank] = r0.w;
            s_obj[rank] = r1.x; s_conf[rank] = r1.y;
            s_cls[rank] = (int)r1.z;
        }
    }
    __syncthreads();

    // ---- build suppression bitmask: thread i owns row i ----
    if (tid < nval) {
        const int i = tid;
        float x1 = bx1[i], y1 = by1[i], x2 = bx2[i], y2 = by2[i];
        int   ci = s_cls[i];
        float ai = fmaxf(x2 - x1, 0.f) * fmaxf(y2 - y1, 0.f);
        for (int j = i + 1; j < nval; ++j) {
            if (s_cls[j] != ci) continue;
            float jx1 = bx1[j], jy1 = by1[j], jx2 = bx2[j], jy2 = by2[j];
            float aj = fmaxf(jx2 - jx1, 0.f) * fmaxf(jy2 - jy1, 0.f);
            float xx1 = fmaxf(x1, jx1), yy1 = fmaxf(y1, jy1);
            float xx2 = fminf(x2, jx2), yy2 = fminf(y2, jy2);
            float ww = fmaxf(xx2 - xx1, 0.f), hh = fmaxf(yy2 - yy1, 0.f);
            float inter = ww * hh;
            float uni = ai + aj - inter;
            float iou = inter / fmaxf(uni, 1e-9f);
            if (iou > NMS_TH) sup[i][j >> 5] |= (1u << (j & 31));
        }
    }
    __syncthreads();

    // ---- sequential greedy pass: one wave, register bitmask sweep ----
    if (tid < 64) {
        const int l = tid;
        unsigned keep_w;
        if ((l + 1) * 32 <= nval)      keep_w = 0xFFFFFFFFu;
        else if (l * 32 >= nval)       keep_w = 0u;
        else                           keep_w = (1u << (nval - l * 32)) - 1u;
        for (int i = 0; i < nval; ++i) {
            int w = i >> 5;
            unsigned kb = (unsigned)__shfl((int)keep_w, w);   // word holding bit i
            unsigned sw = (l < 16) ? sup[i][l] : 0u;
            unsigned mask = ((kb >> (i & 31)) & 1u) ? ~sw : 0xFFFFFFFFu;
            keep_w &= mask;
        }
        if (l < KDET / 32) keepw[l] = keep_w;
    }
    __syncthreads();

    // ---- write outputs (every element, every launch) ----
    if (tid < KDET) {
        const int k = tid;
        float kp = ((keepw[k >> 5] >> (k & 31)) & 1u) ? 1.0f : 0.0f;
        float* d = out_dets + ((size_t)b * KDET + k) * 7;
        d[0] = bx1[k] * kp;
        d[1] = by1[k] * kp;
        d[2] = bx2[k] * kp;
        d[3] = by2[k] * kp;
        d[4] = s_obj[k]  * kp;
        d[5] = s_conf[k] * kp;
        d[6] = (float)s_cls[k] * kp;
        out_keep[(size_t)b * KDET + k] = kp;
    }
}

extern "C" void kernel_launch(void* const* d_in, const int* in_sizes, int n_in,
                              void* d_out, int out_size, void* d_ws, size_t ws_size,
                              hipStream_t stream) {
    const float* pred = (const float*)d_in[0];
    const int A = in_sizes[0] / (NBATCH * CH);   // 22743

    int*   cnt  = (int*)d_ws;                          // 32 counters
    ull*   cand = (ull*)((char*)d_ws + 256);           // 32 x CAP keys (256 KB)
    float* rec  = (float*)((char*)d_ws + 256 + (size_t)NBATCH * CAP * sizeof(ull));
    int cap = CAP;                                     // ws ~1 GB; we need ~1.3 MB

    yolo_zero<<<1, 64, 0, stream>>>(cnt);

    dim3 sg((A + 1023) / 1024, NBATCH);
    yolo_scan_decode<<<sg, 256, 0, stream>>>(pred, A, cap, cand, cnt, rec);

    float* dets = (float*)d_out;                  // [32][512][7]
    float* keep = dets + (size_t)NBATCH * KDET * 7;
    yolo_finalize<<<NBATCH, 1024, 0, stream>>>(cap, cand, cnt, rec, dets, keep);
}